// Round 10
// baseline (134.489 us; speedup 1.0000x reference)
//
#include <hip/hip_runtime.h>
#include <hip/hip_bf16.h>

// Problem constants (B=2, T=2048, C=1024, H=16, hd=64)
#define TT    2048
#define CC    1024
#define N3C   3072
#define MROWS 4096   // B*T

typedef __attribute__((ext_vector_type(8))) short short8;
typedef __attribute__((ext_vector_type(4))) float floatx4;

#define MAX3(a, b, c) fmaxf(fmaxf((a), (b)), (c))

static __device__ __forceinline__ unsigned short f2bf(float f) {
  union { float f; unsigned u; } v; v.f = f;
  return (unsigned short)((v.u + 0x7fffu + ((v.u >> 16) & 1u)) >> 16);
}
static __device__ __forceinline__ unsigned cvt_pk_bf16(float lo, float hi) {
  unsigned r;
  asm("v_cvt_pk_bf16_f32 %0, %1, %2" : "=v"(r) : "v"(lo), "v"(hi));
  return r;
}
static __device__ __forceinline__ float fast_exp2(float x) {
  float r;
  asm("v_exp_f32 %0, %1" : "=v"(r) : "v"(x));
  return r;
}

// ---------------- convert x f32 -> bf16 (xb lives in d_out scratch) ----------------
__global__ __launch_bounds__(256) void k_cvt_x(const float* __restrict__ x,
                                               unsigned short* __restrict__ xb) {
  int i = (blockIdx.x * 256 + threadIdx.x) * 8;
  float4 f0 = *reinterpret_cast<const float4*>(x + i);
  float4 f1 = *reinterpret_cast<const float4*>(x + i + 4);
  union { unsigned u[4]; short8 v; } pk;
  pk.u[0] = cvt_pk_bf16(f0.x, f0.y);
  pk.u[1] = cvt_pk_bf16(f0.z, f0.w);
  pk.u[2] = cvt_pk_bf16(f1.x, f1.y);
  pk.u[3] = cvt_pk_bf16(f1.z, f1.w);
  *reinterpret_cast<short8*>(xb + i) = pk.v;
}

// ---------------- transpose W1 [1024][3072] -> W1t bf16 [3072][1024] ----------------
__global__ __launch_bounds__(256) void k_tr_w1(const float* __restrict__ w,
                                               unsigned short* __restrict__ wt) {
  __shared__ float tile[32][33];
  int k0 = blockIdx.x * 32;   // over K=1024
  int n0 = blockIdx.y * 32;   // over N=3072
  int tx = threadIdx.x & 31;
  int ty = threadIdx.x >> 5;  // 0..7
#pragma unroll
  for (int j = 0; j < 4; ++j)
    tile[ty + 8 * j][tx] = w[(size_t)(k0 + ty + 8 * j) * N3C + n0 + tx];
  __syncthreads();
#pragma unroll
  for (int j = 0; j < 4; ++j)
    wt[(size_t)(n0 + ty + 8 * j) * CC + k0 + tx] = f2bf(tile[tx][ty + 8 * j]);
}

// ---------------- QKV GEMM: xb[4096,1024](bf16) x W1t + b1 -> qkv bf16 ----------------
// 128x128 tile, BK=64, 4 waves. Both operands staged via global_load_lds (16B).
// Q columns (col < CC) pre-scaled by 1/(sqrt(1024)*ln2): attention works in log2 domain.
__global__ __launch_bounds__(256) void k_qkv_gemm(const unsigned short* __restrict__ xb,
                                                  const unsigned short* __restrict__ wt,
                                                  const float* __restrict__ b1,
                                                  unsigned short* __restrict__ qkv) {
  __shared__ unsigned short lA[128 * 64];
  __shared__ unsigned short lB[128 * 64];
  const int tid = threadIdx.x;
  const int bm = blockIdx.x;       // 0..31
  const int bn = blockIdx.y;       // 0..23
  const int wid = tid >> 6, lane = tid & 63;
  const int wr = wid >> 1, wc = wid & 1;
  const int lr = lane & 15;
  const int lg = lane >> 4;
  const int lk = lg * 8;

  floatx4 acc[4][4] = {};

  for (int kt = 0; kt < CC; kt += 64) {
#pragma unroll
    for (int c = 0; c < 4; ++c) {
      int eo = c * 2048 + tid * 8;         // element offset in [128][64] tile
      int row = eo >> 6, col = eo & 63;
      const unsigned short* ga = xb + (size_t)(bm * 128 + row) * CC + kt + col;
      __builtin_amdgcn_global_load_lds((const __attribute__((address_space(1))) void*)ga,
                                       (__attribute__((address_space(3))) void*)(lA + eo), 16, 0, 0);
      const unsigned short* gb = wt + (size_t)(bn * 128 + row) * CC + kt + col;
      __builtin_amdgcn_global_load_lds((const __attribute__((address_space(1))) void*)gb,
                                       (__attribute__((address_space(3))) void*)(lB + eo), 16, 0, 0);
    }
    __syncthreads();
#pragma unroll
    for (int ks = 0; ks < 2; ++ks) {
      short8 a[4], b[4];
#pragma unroll
      for (int m = 0; m < 4; ++m)
        a[m] = *reinterpret_cast<const short8*>(lA + (wr * 64 + m * 16 + lr) * 64 + ks * 32 + lk);
#pragma unroll
      for (int n = 0; n < 4; ++n)
        b[n] = *reinterpret_cast<const short8*>(lB + (wc * 64 + n * 16 + lr) * 64 + ks * 32 + lk);
#pragma unroll
      for (int m = 0; m < 4; ++m)
#pragma unroll
        for (int n = 0; n < 4; ++n)
          acc[m][n] = __builtin_amdgcn_mfma_f32_16x16x32_bf16(a[m], b[n], acc[m][n], 0, 0, 0);
    }
    __syncthreads();
  }

  const int rowb = bm * 128 + wr * 64;
  const int colb = bn * 128 + wc * 64;
#pragma unroll
  for (int n = 0; n < 4; ++n) {
    int col = colb + n * 16 + lr;
    float bias = b1[col];
    // Q: fold 1/sqrt(d_model) AND 1/ln2 (log2-domain softmax) = 0.03125/ln2
    float scl = (col < CC) ? 0.045084372f : 1.0f;
#pragma unroll
    for (int m = 0; m < 4; ++m)
#pragma unroll
      for (int r = 0; r < 4; ++r) {
        int row = rowb + m * 16 + lg * 4 + r;
        qkv[(size_t)row * N3C + col] = f2bf((acc[m][n][r] + bias) * scl);
      }
  }
}

// ---------------- Flash attention: qkv bf16 -> sdp f32 [4096][1024] (in d_out) ----------------
// block = 64 q x 64-key tiles of one (b,h); 4 waves in a 2x2 (key-half W, q-half qh) grid:
// wave handles 32 keys x 32 queries. Frag reads per wave-tile: 4 K + 4 V (vs 16 in q-split).
// S^T layout puts q = lane&15 -> softmax stats fully PER-LANE (no shuffles steady-state,
// alpha rescale in-lane, l reduced at epilogue). sigma-permuted V columns
// (phys key (W,kh,g,r) -> col 32W+8g+4kh+r) make P->B-frag a pure in-lane cvt_pk pack.
// Per-wave partials over the key-half are flash-combined at the epilogue via LDS exchange.
__global__ __launch_bounds__(256) void k_attn(const unsigned short* __restrict__ qkv,
                                              float* __restrict__ sdp) {
  __shared__ unsigned short lsm[4 * 4096];   // lK[2] | lVt[2]; reused as f32 xch in epilogue
  unsigned short* lK  = lsm;                 // [2][64*64] rows=phys key, cols=d (swizzled)
  unsigned short* lVt = lsm + 2 * 4096;      // [2][64*64] rows=d, cols=sigma(key) (swizzled)

  const int tid = threadIdx.x;
  const int lane = tid & 63, wid = tid >> 6;
  const int lr = lane & 15;
  const int lg = lane >> 4;          // 0..3
  const int lk = lg * 8;
  const int swm = (lr & 7) << 3;     // read-side swizzle mask (row&7 == lr&7 everywhere)

  const int W  = wid >> 1;           // key-half: keys 32W .. 32W+31
  const int qh = wid & 1;            // q-half within block

  // XCD-aware remap (bijective): all 32 qb-blocks of one head share an XCD L2.
  const int bid = blockIdx.x;
  const int jj  = bid >> 3;
  const int hh  = (bid & 7) + 8 * (jj >> 5);   // 0..31 = b*16+h
  const int qb  = jj & 31;
  const int h   = hh & 15;
  const int b   = hh >> 4;

  const int qrow0 = qb * 64 + qh * 32;

  // Q fragments: aq[qb2][ks]; lane holds Q[q = qrow0+16*qb2+lr][d = 32*ks+8*lg+j]
  short8 aq[2][2];
#pragma unroll
  for (int qb2 = 0; qb2 < 2; ++qb2) {
    const size_t qbase = ((size_t)(b * TT + qrow0 + 16 * qb2 + lr)) * N3C + h * 64;
    aq[qb2][0] = *reinterpret_cast<const short8*>(qkv + qbase + lk);
    aq[qb2][1] = *reinterpret_cast<const short8*>(qkv + qbase + 32 + lk);
  }

  floatx4 o[2][4] = {};                     // o[qb2][n]: d = 16n+4lg+r, q = qrow0+16qb2+lr
  float m[2] = {-1e30f, -1e30f};            // per-lane running max (log2), q = ...+lr
  float l[2] = {0.f, 0.f};                  // per-lane partial denominator

  // K staging geometry (global source pre-swizzled, LDS dest linear)
  const int keo0 = tid * 8;
  const int krow0 = keo0 >> 6, kcol0 = (keo0 & 63) ^ ((krow0 & 7) << 3);
  const int keo1 = 2048 + tid * 8;
  const int krow1 = keo1 >> 6, kcol1 = (keo1 & 63) ^ ((krow1 & 7) << 3);
  const size_t kbase = (size_t)(b * TT) * N3C + CC + h * 64;

  // V staging: thread handles phys keys (2kp, 2kp+1) x 8 d (db*8..+7), b32 pair writes
  // at sigma columns: phys k -> col 32*W + 8*g + 4*kh + r (pair -> adjacent cols).
  const int kp = tid & 31;
  const int db = tid >> 5;
  const int vcol0 = 32 * (kp >> 4) + 8 * ((kp >> 1) & 3) + 4 * ((kp >> 3) & 1) + 2 * (kp & 1);
  const size_t vbase = ((size_t)(b * TT + 2 * kp)) * N3C + 2 * CC + h * 64 + db * 8;

  // ---- prologue: stage tile 0 ----
  {
    const unsigned short* g0 = qkv + kbase + (size_t)krow0 * N3C + kcol0;
    __builtin_amdgcn_global_load_lds((const __attribute__((address_space(1))) void*)g0,
                                     (__attribute__((address_space(3))) void*)(lK + keo0), 16, 0, 0);
    const unsigned short* g1 = qkv + kbase + (size_t)krow1 * N3C + kcol1;
    __builtin_amdgcn_global_load_lds((const __attribute__((address_space(1))) void*)g1,
                                     (__attribute__((address_space(3))) void*)(lK + keo1), 16, 0, 0);
    short8 v0 = *reinterpret_cast<const short8*>(qkv + vbase);
    short8 v1 = *reinterpret_cast<const short8*>(qkv + vbase + N3C);
#pragma unroll
    for (int j = 0; j < 8; ++j) {
      int rr = db * 8 + j;
      unsigned wrd = ((unsigned)(unsigned short)v0[j]) | (((unsigned)(unsigned short)v1[j]) << 16);
      *reinterpret_cast<unsigned*>(&lVt[rr * 64 + (vcol0 ^ ((rr & 7) << 3))]) = wrd;
    }
  }
  __syncthreads();

  for (int kt = 0; kt < TT / 64; ++kt) {
    const int cur = kt & 1;
    short8 nv0, nv1;
    if (kt < TT / 64 - 1) {
      const size_t koff = kbase + (size_t)((kt + 1) * 64) * N3C;
      const unsigned short* g0 = qkv + koff + (size_t)krow0 * N3C + kcol0;
      __builtin_amdgcn_global_load_lds((const __attribute__((address_space(1))) void*)g0,
                                       (__attribute__((address_space(3))) void*)(lK + (cur ^ 1) * 4096 + keo0), 16, 0, 0);
      const unsigned short* g1 = qkv + koff + (size_t)krow1 * N3C + kcol1;
      __builtin_amdgcn_global_load_lds((const __attribute__((address_space(1))) void*)g1,
                                       (__attribute__((address_space(3))) void*)(lK + (cur ^ 1) * 4096 + keo1), 16, 0, 0);
      const unsigned short* gv = qkv + vbase + (size_t)((kt + 1) * 64) * N3C;
      nv0 = *reinterpret_cast<const short8*>(gv);
      nv1 = *reinterpret_cast<const short8*>(gv + N3C);
    }

    // ---- QK^T: s[kh][qb2], lane holds S[key = 32W+16kh+4lg+r][q = qrow0+16qb2+lr] ----
    floatx4 s[2][2];
    __builtin_amdgcn_s_setprio(1);
#pragma unroll
    for (int kh = 0; kh < 2; ++kh) {
      const unsigned short* krow = lK + cur * 4096 + (32 * W + 16 * kh + lr) * 64;
      short8 kf0 = *reinterpret_cast<const short8*>(krow + ((0 + lk) ^ swm));
      short8 kf1 = *reinterpret_cast<const short8*>(krow + ((32 + lk) ^ swm));
      floatx4 z0 = {}, z1 = {};
      z0 = __builtin_amdgcn_mfma_f32_16x16x32_bf16(kf0, aq[0][0], z0, 0, 0, 0);
      z0 = __builtin_amdgcn_mfma_f32_16x16x32_bf16(kf1, aq[0][1], z0, 0, 0, 0);
      z1 = __builtin_amdgcn_mfma_f32_16x16x32_bf16(kf0, aq[1][0], z1, 0, 0, 0);
      z1 = __builtin_amdgcn_mfma_f32_16x16x32_bf16(kf1, aq[1][1], z1, 0, 0, 0);
      s[kh][0] = z0;
      s[kh][1] = z1;
    }
    __builtin_amdgcn_s_setprio(0);

    // ---- per-lane softmax (base-2) + pure in-lane P pack; B-frags apc[qb2] ----
    short8 apc[2];
#pragma unroll
    for (int qb2 = 0; qb2 < 2; ++qb2) {
      float v0 = MAX3(s[0][qb2][0], s[0][qb2][1], s[0][qb2][2]);
      float v1 = MAX3(s[0][qb2][3], s[1][qb2][0], s[1][qb2][1]);
      float v2 = fmaxf(s[1][qb2][2], s[1][qb2][3]);
      float pmax = MAX3(v0, v1, v2);

      if (__any(pmax > m[qb2] + 11.5f)) {   // defer-max gate (2^11.5 ~ e^8 headroom)
        float pm = fmaxf(pmax, __shfl_xor(pmax, 16));
        pm = fmaxf(pm, __shfl_xor(pm, 32));
        float mnew = fmaxf(m[qb2], pm);
        float alpha = fast_exp2(m[qb2] - mnew);
        m[qb2] = mnew;
        l[qb2] *= alpha;
#pragma unroll
        for (int n = 0; n < 4; ++n)
#pragma unroll
          for (int r = 0; r < 4; ++r) o[qb2][n][r] *= alpha;   // in-lane: o cols are this q
      }

      float p0[4], p1[4];
#pragma unroll
      for (int r = 0; r < 4; ++r) {
        p0[r] = fast_exp2(s[0][qb2][r] - m[qb2]);
        p1[r] = fast_exp2(s[1][qb2][r] - m[qb2]);
      }
      l[qb2] += ((p0[0] + p0[1]) + (p0[2] + p0[3])) + ((p1[0] + p1[1]) + (p1[2] + p1[3]));

      // B-frag: k-slot j = 4*kh + r  (sigma relabel) -> pure in-lane pack
      union { unsigned u[4]; short8 v; } c;
      c.u[0] = cvt_pk_bf16(p0[0], p0[1]);
      c.u[1] = cvt_pk_bf16(p0[2], p0[3]);
      c.u[2] = cvt_pk_bf16(p1[0], p1[1]);
      c.u[3] = cvt_pk_bf16(p1[2], p1[3]);
      apc[qb2] = c.v;
    }

    // ---- PV: o[qb2][n] += mfma(A = V^T-frag[n], B = apc[qb2]) over 32 keys ----
    __builtin_amdgcn_s_setprio(1);
#pragma unroll
    for (int n = 0; n < 4; ++n) {
      short8 vf = *reinterpret_cast<const short8*>(
          lVt + cur * 4096 + (16 * n + lr) * 64 + ((32 * W + lk) ^ swm));
      o[0][n] = __builtin_amdgcn_mfma_f32_16x16x32_bf16(vf, apc[0], o[0][n], 0, 0, 0);
      o[1][n] = __builtin_amdgcn_mfma_f32_16x16x32_bf16(vf, apc[1], o[1][n], 0, 0, 0);
    }
    __builtin_amdgcn_s_setprio(0);

    // ---- write next V tile (b32 key-pairs at sigma columns), then one barrier ----
    if (kt < TT / 64 - 1) {
#pragma unroll
      for (int j = 0; j < 8; ++j) {
        int rr = db * 8 + j;
        unsigned wrd = ((unsigned)(unsigned short)nv0[j]) | (((unsigned)(unsigned short)nv1[j]) << 16);
        *reinterpret_cast<unsigned*>(&lVt[(cur ^ 1) * 4096 + rr * 64 + (vcol0 ^ ((rr & 7) << 3))]) = wrd;
      }
    }
    __syncthreads();  // drains vmcnt (K stage) + makes V writes visible
  }

  // ---- epilogue: reduce l across lg lanes, flash-combine the two key-halves ----
  float lt[2];
#pragma unroll
  for (int qb2 = 0; qb2 < 2; ++qb2) {
    float t = l[qb2] + __shfl_xor(l[qb2], 16);
    lt[qb2] = t + __shfl_xor(t, 32);
  }

  float* xch = (float*)lsm;                      // 32KB scratch (K/V dead now)
  const int base = (qh * 64 + lane) * 37;        // 37-stride: conflict-light
  if (W == 1) {
#pragma unroll
    for (int qb2 = 0; qb2 < 2; ++qb2) {
#pragma unroll
      for (int n = 0; n < 4; ++n)
#pragma unroll
        for (int r = 0; r < 4; ++r) xch[base + qb2 * 18 + n * 4 + r] = o[qb2][n][r];
      xch[base + qb2 * 18 + 16] = m[qb2];
      xch[base + qb2 * 18 + 17] = lt[qb2];
    }
  }
  __syncthreads();
  if (W == 0) {
#pragma unroll
    for (int qb2 = 0; qb2 < 2; ++qb2) {
      float mb = xch[base + qb2 * 18 + 16];
      float lb = xch[base + qb2 * 18 + 17];
      float M  = fmaxf(m[qb2], mb);
      float sa = fast_exp2(m[qb2] - M);
      float sb = fast_exp2(mb - M);
      float inv = 1.0f / (lt[qb2] * sa + lb * sb);
      const size_t rowbase = ((size_t)(b * TT + qrow0 + 16 * qb2 + lr)) * CC + h * 64;
#pragma unroll
      for (int n = 0; n < 4; ++n)
#pragma unroll
        for (int r = 0; r < 4; ++r) {
          float ob = xch[base + qb2 * 18 + n * 4 + r];
          sdp[rowbase + 16 * n + 4 * lg + r] = (o[qb2][n][r] * sa + ob * sb) * inv;
        }
    }
  }
}

// ---------------- residual + LayerNorm, in-place on io (f32 sdp -> f32 out) ----------------
__global__ __launch_bounds__(256) void k_ln(const float* __restrict__ x,
                                            const float* __restrict__ gamma,
                                            const float* __restrict__ beta,
                                            float* io) {
  __shared__ float red[2][4];
  const int row = blockIdx.x;
  const int tid = threadIdx.x;
  const int i0 = tid * 4;
  float4 xv = *reinterpret_cast<const float4*>(x + (size_t)row * CC + i0);
  float4 sv = *reinterpret_cast<const float4*>(io + (size_t)row * CC + i0);
  float y[4] = {xv.x + sv.x, xv.y + sv.y, xv.z + sv.z, xv.w + sv.w};
  float s = y[0] + y[1] + y[2] + y[3];
  float s2 = y[0] * y[0] + y[1] * y[1] + y[2] * y[2] + y[3] * y[3];
#pragma unroll
  for (int msk = 1; msk < 64; msk <<= 1) {
    s += __shfl_xor(s, msk);
    s2 += __shfl_xor(s2, msk);
  }
  const int wid = tid >> 6;
  if ((tid & 63) == 0) { red[0][wid] = s; red[1][wid] = s2; }
  __syncthreads();
  s = red[0][0] + red[0][1] + red[0][2] + red[0][3];
  s2 = red[1][0] + red[1][1] + red[1][2] + red[1][3];
  float mean = s * (1.0f / CC);
  float var = s2 * (1.0f / CC) - mean * mean;
  float rstd = rsqrtf(var + 1e-6f);
  float4 r;
  r.x = (y[0] - mean) * rstd * gamma[i0 + 0] + beta[i0 + 0];
  r.y = (y[1] - mean) * rstd * gamma[i0 + 1] + beta[i0 + 1];
  r.z = (y[2] - mean) * rstd * gamma[i0 + 2] + beta[i0 + 2];
  r.w = (y[3] - mean) * rstd * gamma[i0 + 3] + beta[i0 + 3];
  *reinterpret_cast<float4*>(io + (size_t)row * CC + i0) = r;
}

extern "C" void kernel_launch(void* const* d_in, const int* in_sizes, int n_in,
                              void* d_out, int out_size, void* d_ws, size_t ws_size,
                              hipStream_t stream) {
  const float* x     = (const float*)d_in[0];
  const float* W1    = (const float*)d_in[1];
  const float* b1    = (const float*)d_in[2];
  const float* gamma = (const float*)d_in[3];
  const float* beta  = (const float*)d_in[4];

  // Memory plan: qkv bf16 (25.2 MB) is the ONLY d_ws user.
  // d_out (16.78 MB f32) doubles as scratch:
  //   [0, 6.29MB)      W1t bf16   (dead after GEMM)
  //   [6.29, 14.68MB)  xb bf16    (dead after GEMM)
  // then k_attn overwrites all of d_out with sdp f32; LN runs in-place.
  unsigned short* qkv = (unsigned short*)d_ws;
  unsigned short* w1t = (unsigned short*)d_out;
  unsigned short* xb  = (unsigned short*)((char*)d_out + 6291456);
  float*          sdp = (float*)d_out;

  k_cvt_x<<<MROWS * CC / (256 * 8), 256, 0, stream>>>(x, xb);
  k_tr_w1<<<dim3(CC / 32, N3C / 32), 256, 0, stream>>>(W1, w1t);
  k_qkv_gemm<<<dim3(MROWS / 128, N3C / 128), 256, 0, stream>>>(xb, w1t, b1, qkv);
  k_attn<<<2 * 16 * (TT / 64), 256, 0, stream>>>(qkv, sdp);
  k_ln<<<MROWS, 256, 0, stream>>>(x, gamma, beta, sdp);
}

// Round 11
// 129.366 us; speedup vs baseline: 1.0396x; 1.0396x over previous
//
#include <hip/hip_runtime.h>
#include <hip/hip_bf16.h>

// Problem constants (B=2, T=2048, C=1024, H=16, hd=64)
#define TT    2048
#define CC    1024
#define N3C   3072
#define MROWS 4096   // B*T

typedef __attribute__((ext_vector_type(8))) short short8;
typedef __attribute__((ext_vector_type(4))) float floatx4;

#define MAX3(a, b, c) fmaxf(fmaxf((a), (b)), (c))

static __device__ __forceinline__ unsigned short f2bf(float f) {
  union { float f; unsigned u; } v; v.f = f;
  return (unsigned short)((v.u + 0x7fffu + ((v.u >> 16) & 1u)) >> 16);
}
static __device__ __forceinline__ unsigned cvt_pk_bf16(float lo, float hi) {
  unsigned r;
  asm("v_cvt_pk_bf16_f32 %0, %1, %2" : "=v"(r) : "v"(lo), "v"(hi));
  return r;
}
static __device__ __forceinline__ float fast_exp2(float x) {
  float r;
  asm("v_exp_f32 %0, %1" : "=v"(r) : "v"(x));
  return r;
}

// ---------------- prep: x f32->bf16 convert  +  W1 transpose, one launch ----------------
// blocks [0,2048): convert x (8 f32/thread). blocks [2048,5120): 32x32 transpose tiles.
__global__ __launch_bounds__(256) void k_prep(const float* __restrict__ x,
                                              const float* __restrict__ w,
                                              unsigned short* __restrict__ xb,
                                              unsigned short* __restrict__ wt) {
  __shared__ float tile[32][33];
  const int bx = blockIdx.x;
  if (bx < 2048) {
    int i = (bx * 256 + threadIdx.x) * 8;
    float4 f0 = *reinterpret_cast<const float4*>(x + i);
    float4 f1 = *reinterpret_cast<const float4*>(x + i + 4);
    union { unsigned u[4]; short8 v; } pk;
    pk.u[0] = cvt_pk_bf16(f0.x, f0.y);
    pk.u[1] = cvt_pk_bf16(f0.z, f0.w);
    pk.u[2] = cvt_pk_bf16(f1.x, f1.y);
    pk.u[3] = cvt_pk_bf16(f1.z, f1.w);
    *reinterpret_cast<short8*>(xb + i) = pk.v;
  } else {
    const int t = bx - 2048;
    const int k0 = (t & 31) * 32;   // over K=1024
    const int n0 = (t >> 5) * 32;   // over N=3072
    const int tx = threadIdx.x & 31;
    const int ty = threadIdx.x >> 5;  // 0..7
#pragma unroll
    for (int j = 0; j < 4; ++j)
      tile[ty + 8 * j][tx] = w[(size_t)(k0 + ty + 8 * j) * N3C + n0 + tx];
    __syncthreads();
#pragma unroll
    for (int j = 0; j < 4; ++j)
      wt[(size_t)(n0 + ty + 8 * j) * CC + k0 + tx] = f2bf(tile[tx][ty + 8 * j]);
  }
}

// ---------------- QKV GEMM: xb[4096,1024](bf16) x W1t + b1 -> qkv bf16 ----------------
// 128x128 tile, BK=64, 4 waves. Both operands staged via global_load_lds (16B).
// Q columns (col < CC) pre-scaled by 1/(sqrt(1024)*ln2): attention works in log2 domain.
__global__ __launch_bounds__(256) void k_qkv_gemm(const unsigned short* __restrict__ xb,
                                                  const unsigned short* __restrict__ wt,
                                                  const float* __restrict__ b1,
                                                  unsigned short* __restrict__ qkv) {
  __shared__ unsigned short lA[128 * 64];
  __shared__ unsigned short lB[128 * 64];
  const int tid = threadIdx.x;
  const int bm = blockIdx.x;       // 0..31
  const int bn = blockIdx.y;       // 0..23
  const int wid = tid >> 6, lane = tid & 63;
  const int wr = wid >> 1, wc = wid & 1;
  const int lr = lane & 15;
  const int lg = lane >> 4;
  const int lk = lg * 8;

  floatx4 acc[4][4] = {};

  for (int kt = 0; kt < CC; kt += 64) {
#pragma unroll
    for (int c = 0; c < 4; ++c) {
      int eo = c * 2048 + tid * 8;         // element offset in [128][64] tile
      int row = eo >> 6, col = eo & 63;
      const unsigned short* ga = xb + (size_t)(bm * 128 + row) * CC + kt + col;
      __builtin_amdgcn_global_load_lds((const __attribute__((address_space(1))) void*)ga,
                                       (__attribute__((address_space(3))) void*)(lA + eo), 16, 0, 0);
      const unsigned short* gb = wt + (size_t)(bn * 128 + row) * CC + kt + col;
      __builtin_amdgcn_global_load_lds((const __attribute__((address_space(1))) void*)gb,
                                       (__attribute__((address_space(3))) void*)(lB + eo), 16, 0, 0);
    }
    __syncthreads();
#pragma unroll
    for (int ks = 0; ks < 2; ++ks) {
      short8 a[4], b[4];
#pragma unroll
      for (int m = 0; m < 4; ++m)
        a[m] = *reinterpret_cast<const short8*>(lA + (wr * 64 + m * 16 + lr) * 64 + ks * 32 + lk);
#pragma unroll
      for (int n = 0; n < 4; ++n)
        b[n] = *reinterpret_cast<const short8*>(lB + (wc * 64 + n * 16 + lr) * 64 + ks * 32 + lk);
#pragma unroll
      for (int m = 0; m < 4; ++m)
#pragma unroll
        for (int n = 0; n < 4; ++n)
          acc[m][n] = __builtin_amdgcn_mfma_f32_16x16x32_bf16(a[m], b[n], acc[m][n], 0, 0, 0);
    }
    __syncthreads();
  }

  const int rowb = bm * 128 + wr * 64;
  const int colb = bn * 128 + wc * 64;
#pragma unroll
  for (int n = 0; n < 4; ++n) {
    int col = colb + n * 16 + lr;
    float bias = b1[col];
    // Q: fold 1/sqrt(d_model) AND 1/ln2 (log2-domain softmax) = 0.03125/ln2
    float scl = (col < CC) ? 0.045084372f : 1.0f;
#pragma unroll
    for (int m = 0; m < 4; ++m)
#pragma unroll
      for (int r = 0; r < 4; ++r) {
        int row = rowb + m * 16 + lg * 4 + r;
        qkv[(size_t)row * N3C + col] = f2bf((acc[m][n][r] + bias) * scl);
      }
  }
}

// ---------------- Flash attention: qkv bf16 -> sdp f32 [4096][1024] (in d_out) ----------------
// (Round-9 structure — best measured.) block = 64 q-rows of one (b,h); 4 waves x 16 q.
// Swapped QK^T (S^T = K Q^T, log2 domain); per-lane softmax with in-lane partial l
// and branch-gated pmax reduce; sigma-permuted V -> P->A relayout pure in-lane;
// XCD-aware block remap for K/V L2 residency.
__global__ __launch_bounds__(256) void k_attn(const unsigned short* __restrict__ qkv,
                                              float* __restrict__ sdp) {
  __shared__ unsigned short lK[2][64 * 64];
  __shared__ unsigned short lVt[2][64 * 64];   // transposed: [hd][sigma(key)], swizzled

  const int tid = threadIdx.x;
  const int lane = tid & 63, wid = tid >> 6;
  const int lr = lane & 15;
  const int lg = lane >> 4;          // 0..3
  const int lk = lg * 8;
  const int swm = (lr & 7) << 3;     // read-side swizzle mask

  // XCD-aware remap (bijective): all 32 qb-blocks of one head share an XCD L2.
  const int bid = blockIdx.x;
  const int jj  = bid >> 3;
  const int hh  = (bid & 7) + 8 * (jj >> 5);   // 0..31 = b*16+h
  const int qb  = jj & 31;
  const int h   = hh & 15;
  const int b   = hh >> 4;

  const int qrow0 = qb * 64 + wid * 16;
  const size_t qbase = ((size_t)(b * TT + qrow0 + lr)) * N3C + h * 64;

  short8 aq[2];
  aq[0] = *reinterpret_cast<const short8*>(qkv + qbase + lk);
  aq[1] = *reinterpret_cast<const short8*>(qkv + qbase + 32 + lk);

  floatx4 o[4] = {};
  float m = -1e30f;        // running max for q=lr (log2 domain, synced across lg-lanes)
  float l = 0.f;           // PER-LANE partial denominator (this lane's keys only)

  const int qown = lg * 4;                 // o-domain q base (rows qown..qown+3)
  const int statbase = (lane & 48) + qown; // lane holding stats for q=qown+r: statbase+r

  // K staging geometry (global source pre-swizzled, LDS dest linear)
  const int keo0 = tid * 8;
  const int krow0 = keo0 >> 6, kcol0 = (keo0 & 63) ^ ((krow0 & 7) << 3);
  const int keo1 = 2048 + tid * 8;
  const int krow1 = keo1 >> 6, kcol1 = (keo1 & 63) ^ ((krow1 & 7) << 3);
  const size_t kbase = (size_t)(b * TT) * N3C + CC + h * 64;

  // V staging: thread handles global keys (2kp, 2kp+1) x 8 d-values (db*8..+7),
  // written to lVt columns (vsig, vsig+1) where vsig = sigma(2kp).
  const int kp = tid & 31;
  const int db = tid >> 5;
  const int vsig = 32 * ((kp >> 3) & 1) + 8 * ((kp >> 1) & 3) + 4 * (kp >> 4) + 2 * (kp & 1);
  const size_t vbase = ((size_t)(b * TT + 2 * kp)) * N3C + 2 * CC + h * 64 + db * 8;

  // ---- prologue: stage tile 0 ----
  {
    const unsigned short* g0 = qkv + kbase + (size_t)krow0 * N3C + kcol0;
    __builtin_amdgcn_global_load_lds((const __attribute__((address_space(1))) void*)g0,
                                     (__attribute__((address_space(3))) void*)(&lK[0][0] + keo0), 16, 0, 0);
    const unsigned short* g1 = qkv + kbase + (size_t)krow1 * N3C + kcol1;
    __builtin_amdgcn_global_load_lds((const __attribute__((address_space(1))) void*)g1,
                                     (__attribute__((address_space(3))) void*)(&lK[0][0] + keo1), 16, 0, 0);
    short8 v0 = *reinterpret_cast<const short8*>(qkv + vbase);
    short8 v1 = *reinterpret_cast<const short8*>(qkv + vbase + N3C);
#pragma unroll
    for (int j = 0; j < 8; ++j) {
      int rr = db * 8 + j;
      int col0 = vsig ^ (j << 3);
      unsigned wrd = ((unsigned)(unsigned short)v0[j]) | (((unsigned)(unsigned short)v1[j]) << 16);
      *reinterpret_cast<unsigned*>(&lVt[0][rr * 64 + col0]) = wrd;
    }
  }
  __syncthreads();

  for (int kt = 0; kt < TT / 64; ++kt) {
    const int cur = kt & 1;
    short8 nv0, nv1;
    if (kt < TT / 64 - 1) {
      const size_t koff = kbase + (size_t)((kt + 1) * 64) * N3C;
      const unsigned short* g0 = qkv + koff + (size_t)krow0 * N3C + kcol0;
      __builtin_amdgcn_global_load_lds((const __attribute__((address_space(1))) void*)g0,
                                       (__attribute__((address_space(3))) void*)(&lK[cur ^ 1][0] + keo0), 16, 0, 0);
      const unsigned short* g1 = qkv + koff + (size_t)krow1 * N3C + kcol1;
      __builtin_amdgcn_global_load_lds((const __attribute__((address_space(1))) void*)g1,
                                       (__attribute__((address_space(3))) void*)(&lK[cur ^ 1][0] + keo1), 16, 0, 0);
      const unsigned short* gv = qkv + vbase + (size_t)((kt + 1) * 64) * N3C;
      nv0 = *reinterpret_cast<const short8*>(gv);
      nv1 = *reinterpret_cast<const short8*>(gv + N3C);
    }

    // ---- S^T = K Q^T : lane holds S[key = 16n + 4lg + r][q = lr] (log2 domain) ----
    floatx4 s[4];
    __builtin_amdgcn_s_setprio(1);
#pragma unroll
    for (int n = 0; n < 4; ++n) {
      floatx4 z = {};
#pragma unroll
      for (int ks = 0; ks < 2; ++ks) {
        short8 bk = *reinterpret_cast<const short8*>(
            &lK[cur][0] + (n * 16 + lr) * 64 + ((ks * 32 + lk) ^ swm));
        z = __builtin_amdgcn_mfma_f32_16x16x32_bf16(bk, aq[ks], z, 0, 0, 0);
      }
      s[n] = z;
    }
    __builtin_amdgcn_s_setprio(0);

    // ---- per-lane online softmax (base-2): in-lane max over this lane's 16 keys ----
    float a0 = MAX3(s[0][0], s[0][1], s[0][2]);
    float a1 = MAX3(s[0][3], s[1][0], s[1][1]);
    float a2 = MAX3(s[1][2], s[1][3], s[2][0]);
    float a3 = MAX3(s[2][1], s[2][2], s[2][3]);
    float a4 = MAX3(s[3][0], s[3][1], s[3][2]);
    float pmax = fmaxf(MAX3(a0, a1, a2), MAX3(a3, a4, s[3][3]));

    // Branch-gated: cross-lane reduce + rescale only if some lane exceeds headroom.
    if (__any(pmax > m + 11.5f)) {        // defer-max (2^11.5 ~ e^8 headroom)
      float pm = fmaxf(pmax, __shfl_xor(pmax, 16));
      pm = fmaxf(pm, __shfl_xor(pm, 32));
      float mnew = fmaxf(m, pm);
      float alpha = fast_exp2(m - mnew);  // same for all 4 lg-lanes of this q
      m = mnew;
      l *= alpha;                         // per-lane partial l rescales in-lane
      float b0 = __shfl(alpha, statbase + 0);
      float b1_ = __shfl(alpha, statbase + 1);
      float b2 = __shfl(alpha, statbase + 2);
      float b3 = __shfl(alpha, statbase + 3);
#pragma unroll
      for (int n = 0; n < 4; ++n) {
        o[n][0] *= b0; o[n][1] *= b1_; o[n][2] *= b2; o[n][3] *= b3;
      }
    }

    // exp + tree-sum (depth 4, no cross-lane reduce here)
    float p[4][4];
#pragma unroll
    for (int n = 0; n < 4; ++n)
#pragma unroll
      for (int r = 0; r < 4; ++r)
        p[n][r] = fast_exp2(s[n][r] - m);
    float t0 = (p[0][0] + p[0][1]) + (p[0][2] + p[0][3]);
    float t1 = (p[1][0] + p[1][1]) + (p[1][2] + p[1][3]);
    float t2 = (p[2][0] + p[2][1]) + (p[2][2] + p[2][3]);
    float t3 = (p[3][0] + p[3][1]) + (p[3][2] + p[3][3]);
    l += (t0 + t1) + (t2 + t3);

    // ---- P -> A-fragments, PURE IN-LANE (sigma-permuted V makes this legal) ----
    union { unsigned u[4]; short8 v; } c0, c1;
#pragma unroll
    for (int w = 0; w < 4; ++w) {
      int nb = 2 * (w >> 1);
      int rb = 2 * (w & 1);
      c0.u[w] = cvt_pk_bf16(p[nb + 0][rb], p[nb + 0][rb + 1]);
      c1.u[w] = cvt_pk_bf16(p[nb + 1][rb], p[nb + 1][rb + 1]);
    }

    // ---- PV: o[q=4lg+r][d=n*16+lr] += A x V(sigma) ----
    __builtin_amdgcn_s_setprio(1);
#pragma unroll
    for (int n = 0; n < 4; ++n) {
      short8 bv0 = *reinterpret_cast<const short8*>(
          &lVt[cur][0] + (n * 16 + lr) * 64 + ((0 + lk) ^ swm));
      o[n] = __builtin_amdgcn_mfma_f32_16x16x32_bf16(c0.v, bv0, o[n], 0, 0, 0);
      short8 bv1 = *reinterpret_cast<const short8*>(
          &lVt[cur][0] + (n * 16 + lr) * 64 + ((32 + lk) ^ swm));
      o[n] = __builtin_amdgcn_mfma_f32_16x16x32_bf16(c1.v, bv1, o[n], 0, 0, 0);
    }
    __builtin_amdgcn_s_setprio(0);

    // ---- write next V tile (b32 key-pairs at sigma columns), then one barrier ----
    if (kt < TT / 64 - 1) {
#pragma unroll
      for (int j = 0; j < 8; ++j) {
        int rr = db * 8 + j;
        int col0 = vsig ^ (j << 3);
        unsigned wrd = ((unsigned)(unsigned short)nv0[j]) | (((unsigned)(unsigned short)nv1[j]) << 16);
        *reinterpret_cast<unsigned*>(&lVt[cur ^ 1][rr * 64 + col0]) = wrd;
      }
    }
    __syncthreads();  // drains vmcnt (K stage) + makes V writes visible
  }

  // epilogue: reduce per-lane l across the 4 lg-lanes, broadcast 1/l, write sdp (f32)
  float lt = l + __shfl_xor(l, 16);
  lt += __shfl_xor(lt, 32);
  float linv = 1.0f / lt;
  float li0 = __shfl(linv, statbase + 0);
  float li1 = __shfl(linv, statbase + 1);
  float li2 = __shfl(linv, statbase + 2);
  float li3 = __shfl(linv, statbase + 3);
  const int orow0 = b * TT + qrow0 + qown;
#pragma unroll
  for (int n = 0; n < 4; ++n) {
    sdp[(size_t)(orow0 + 0) * CC + h * 64 + n * 16 + lr] = o[n][0] * li0;
    sdp[(size_t)(orow0 + 1) * CC + h * 64 + n * 16 + lr] = o[n][1] * li1;
    sdp[(size_t)(orow0 + 2) * CC + h * 64 + n * 16 + lr] = o[n][2] * li2;
    sdp[(size_t)(orow0 + 3) * CC + h * 64 + n * 16 + lr] = o[n][3] * li3;
  }
}

// ---------------- residual + LayerNorm: one WAVE per row (no LDS, no barrier) ----------------
// 256 threads = 4 waves = 4 rows/block. Lane j handles elems {j*4 + k*256 : k=0..3}
// (stride-256 float4 sweeps -> perfectly coalesced). In-place on io.
__global__ __launch_bounds__(256) void k_ln(const float* __restrict__ x,
                                            const float* __restrict__ gamma,
                                            const float* __restrict__ beta,
                                            float* io) {
  const int tid = threadIdx.x;
  const int lane = tid & 63, wv = tid >> 6;
  const int row = blockIdx.x * 4 + wv;
  const size_t rb = (size_t)row * CC;

  float4 xv[4], sv[4], y[4];
  float s = 0.f, s2 = 0.f;
#pragma unroll
  for (int k = 0; k < 4; ++k) {
    int off = lane * 4 + k * 256;
    xv[k] = *reinterpret_cast<const float4*>(x + rb + off);
    sv[k] = *reinterpret_cast<const float4*>(io + rb + off);
    y[k].x = xv[k].x + sv[k].x; y[k].y = xv[k].y + sv[k].y;
    y[k].z = xv[k].z + sv[k].z; y[k].w = xv[k].w + sv[k].w;
    s  += (y[k].x + y[k].y) + (y[k].z + y[k].w);
    s2 += (y[k].x * y[k].x + y[k].y * y[k].y) + (y[k].z * y[k].z + y[k].w * y[k].w);
  }
#pragma unroll
  for (int msk = 1; msk < 64; msk <<= 1) {
    s += __shfl_xor(s, msk);
    s2 += __shfl_xor(s2, msk);
  }
  float mean = s * (1.0f / CC);
  float var = s2 * (1.0f / CC) - mean * mean;
  float rstd = rsqrtf(var + 1e-6f);
#pragma unroll
  for (int k = 0; k < 4; ++k) {
    int off = lane * 4 + k * 256;
    float4 gv = *reinterpret_cast<const float4*>(gamma + off);
    float4 bv = *reinterpret_cast<const float4*>(beta + off);
    float4 r;
    r.x = (y[k].x - mean) * rstd * gv.x + bv.x;
    r.y = (y[k].y - mean) * rstd * gv.y + bv.y;
    r.z = (y[k].z - mean) * rstd * gv.z + bv.z;
    r.w = (y[k].w - mean) * rstd * gv.w + bv.w;
    *reinterpret_cast<float4*>(io + rb + off) = r;
  }
}

extern "C" void kernel_launch(void* const* d_in, const int* in_sizes, int n_in,
                              void* d_out, int out_size, void* d_ws, size_t ws_size,
                              hipStream_t stream) {
  const float* x     = (const float*)d_in[0];
  const float* W1    = (const float*)d_in[1];
  const float* b1    = (const float*)d_in[2];
  const float* gamma = (const float*)d_in[3];
  const float* beta  = (const float*)d_in[4];

  // Memory plan: qkv bf16 (25.2 MB) is the ONLY d_ws user.
  // d_out (16.78 MB f32) doubles as scratch:
  //   [0, 6.29MB)      W1t bf16   (dead after GEMM)
  //   [6.29, 14.68MB)  xb bf16    (dead after GEMM)
  // then k_attn overwrites all of d_out with sdp f32; LN runs in-place.
  unsigned short* qkv = (unsigned short*)d_ws;
  unsigned short* w1t = (unsigned short*)d_out;
  unsigned short* xb  = (unsigned short*)((char*)d_out + 6291456);
  float*          sdp = (float*)d_out;

  k_prep<<<2048 + 3072, 256, 0, stream>>>(x, W1, xb, w1t);
  k_qkv_gemm<<<dim3(MROWS / 128, N3C / 128), 256, 0, stream>>>(xb, w1t, b1, qkv);
  k_attn<<<2 * 16 * (TT / 64), 256, 0, stream>>>(qkv, sdp);
  k_ln<<<MROWS / 4, 256, 0, stream>>>(x, gamma, beta, sdp);
}